// Round 1
// baseline (137.485 us; speedup 1.0000x reference)
//
#include <hip/hip_runtime.h>
#include <math.h>

// One wave (64 lanes) per ray. ray_id is sorted, so each ray is a contiguous
// segment [begin,end) of the M samples. Segment bounds found by binary search
// (half-wave 0 searches lower_bound(ray), half-wave 1 searches lower_bound(ray+1)).
// Per 64-sample chunk: segmented transmittance via wave-wide inclusive cumprod
// (shfl_up ladder), weights = alpha * carry * exclusive_prefix, accumulate
// weight * sigmoid(rgb) in registers; carry multiplies by the chunk product.

#define INTERVAL 0.5f

__global__ __launch_bounds__(256) void voxel_march_kernel(
    const float* __restrict__ density,
    const float* __restrict__ rgb_raw,
    const float* __restrict__ shift,
    const int*   __restrict__ ray_id,
    float* __restrict__ out,
    int M, int N)
{
    const int lane = threadIdx.x & 63;
    const int wave = threadIdx.x >> 6;
    const int ray  = blockIdx.x * 4 + wave;
    if (ray >= N) return;

    const float sh = shift[0];

    // --- segment bounds: lower_bound(ray) in lanes <32, lower_bound(ray+1) in lanes >=32
    int target = ray + (lane >= 32 ? 1 : 0);
    int lo = 0, len = M;
    while (len > 0) {
        int half = len >> 1;
        int mid  = lo + half;
        if (ray_id[mid] < target) { lo = mid + 1; len -= half + 1; }
        else                      { len = half; }
    }
    const int begin = __shfl(lo, 0, 64);
    const int end   = __shfl(lo, 32, 64);

    float carry = 1.0f;            // running transmittance (= alphainv so far)
    float acc0 = 0.0f, acc1 = 0.0f, acc2 = 0.0f;

    for (int base = begin; base < end; base += 64) {
        const int i = base + lane;
        const bool active = (i < end);

        float om = 1.0f, alpha = 0.0f;
        float r0 = 0.0f, r1 = 0.0f, r2 = 0.0f;
        if (active) {
            float x  = density[i] + sh;
            float sp = (x > 20.0f) ? x : log1pf(__expf(x));   // softplus
            float s  = sp * INTERVAL;
            om    = __expf(-s);       // 1 - alpha, exact form
            alpha = -expm1f(-s);      // 1 - exp(-s), stable
            r0 = rgb_raw[3 * i + 0];
            r1 = rgb_raw[3 * i + 1];
            r2 = rgb_raw[3 * i + 2];
        }

        // wave-wide inclusive cumprod of om
        float p = om;
        #pragma unroll
        for (int off = 1; off < 64; off <<= 1) {
            float q = __shfl_up(p, off, 64);
            if (lane >= off) p *= q;
        }
        // exclusive prefix
        float excl = __shfl_up(p, 1, 64);
        if (lane == 0) excl = 1.0f;

        const float w = alpha * (carry * excl);

        // sigmoid(rgb) and accumulate
        acc0 += w * (1.0f / (1.0f + __expf(-r0)));
        acc1 += w * (1.0f / (1.0f + __expf(-r1)));
        acc2 += w * (1.0f / (1.0f + __expf(-r2)));

        carry *= __shfl(p, 63, 64);   // full chunk product (inactive lanes om=1)
    }

    // wave reduction of the three accumulators
    #pragma unroll
    for (int off = 32; off > 0; off >>= 1) {
        acc0 += __shfl_down(acc0, off, 64);
        acc1 += __shfl_down(acc1, off, 64);
        acc2 += __shfl_down(acc2, off, 64);
    }

    if (lane == 0) {
        out[3 * ray + 0] = acc0 + carry;   // + alphainv_last (white background)
        out[3 * ray + 1] = acc1 + carry;
        out[3 * ray + 2] = acc2 + carry;
    }
}

extern "C" void kernel_launch(void* const* d_in, const int* in_sizes, int n_in,
                              void* d_out, int out_size, void* d_ws, size_t ws_size,
                              hipStream_t stream)
{
    const float* density = (const float*)d_in[0];
    const float* rgb_raw = (const float*)d_in[1];
    const float* shift   = (const float*)d_in[2];
    const int*   ray_id  = (const int*)d_in[3];
    float* out = (float*)d_out;

    const int M = in_sizes[0];
    const int N = out_size / 3;

    const int rays_per_block = 4;                 // 256 threads = 4 waves
    const int blocks = (N + rays_per_block - 1) / rays_per_block;
    voxel_march_kernel<<<blocks, 256, 0, stream>>>(density, rgb_raw, shift, ray_id,
                                                   out, M, N);
}

// Round 2
// 129.824 us; speedup vs baseline: 1.0590x; 1.0590x over previous
//
#include <hip/hip_runtime.h>
#include <math.h>

// One wave (64 lanes) per ray, 4 samples per lane (256-sample chunks).
//
// Math: s = softplus(density+shift) * 0.5
//       om = exp(-s) = (1 + exp(x))^(-1/2)  -> rsqrtf(1 + __expf(x))  [2 HW ops]
//       alpha = 1 - om   (== -expm1(-s) exactly)
// Transmittance: per-lane serial cumprod of 4 oms, wave ladder (6 shfl_up) over
// lane products, carry across chunks. weights = alpha * T; accumulate
// weight * sigmoid(rgb) in registers; epilogue wave-reduce; out += alphainv_last.

#define INTERVAL 0.5f   // folded into the 0.5 exponent of rsqrt

__global__ __launch_bounds__(256) void voxel_march_kernel(
    const float* __restrict__ density,
    const float* __restrict__ rgb_raw,
    const float* __restrict__ shift,
    const int*   __restrict__ ray_id,
    float* __restrict__ out,
    int M, int N)
{
    const int lane = threadIdx.x & 63;
    const int wave = threadIdx.x >> 6;
    const int ray  = blockIdx.x * 4 + wave;
    if (ray >= N) return;

    const float sh = shift[0];

    // segment bounds: half-wave 0 finds lower_bound(ray), half-wave 1 lower_bound(ray+1)
    int target = ray + (lane >= 32 ? 1 : 0);
    int lo = 0, len = M;
    while (len > 0) {
        int half = len >> 1;
        int mid  = lo + half;
        if (ray_id[mid] < target) { lo = mid + 1; len -= half + 1; }
        else                      { len = half; }
    }
    const int begin = __shfl(lo, 0, 64);
    const int end   = __shfl(lo, 32, 64);

    float carry = 1.0f;
    float acc0 = 0.0f, acc1 = 0.0f, acc2 = 0.0f;

    for (int base = (begin & ~3); base < end; base += 256) {
        const int b4 = base + 4 * lane;     // first of this lane's 4 samples

        float d0, d1, d2, d3;
        float r[12];

        if (b4 >= begin && b4 + 3 < end) {
            // fast path: all 4 samples in-segment, 16B-aligned vector loads
            const float4 dd = *(const float4*)(density + b4);
            d0 = dd.x; d1 = dd.y; d2 = dd.z; d3 = dd.w;
            const float4* rp = (const float4*)(rgb_raw + 3 * b4);
            float4 a0 = rp[0], a1 = rp[1], a2 = rp[2];
            r[0]=a0.x; r[1]=a0.y; r[2]=a0.z; r[3]=a0.w;
            r[4]=a1.x; r[5]=a1.y; r[6]=a1.z; r[7]=a1.w;
            r[8]=a2.x; r[9]=a2.y; r[10]=a2.z; r[11]=a2.w;
        } else {
            // boundary path: per-sample guarded scalar loads; masked samples get
            // density -inf -> om=1, alpha=0 (identity for scan, zero weight)
            #pragma unroll
            for (int k = 0; k < 4; ++k) {
                const int j = b4 + k;
                const bool act = (j >= begin) && (j < end);
                float dk = act ? density[j] : -1e30f;
                if (k == 0) d0 = dk; else if (k == 1) d1 = dk;
                else if (k == 2) d2 = dk; else d3 = dk;
                r[3*k+0] = act ? rgb_raw[3*j+0] : 0.0f;
                r[3*k+1] = act ? rgb_raw[3*j+1] : 0.0f;
                r[3*k+2] = act ? rgb_raw[3*j+2] : 0.0f;
            }
        }

        // om = (1+e^x)^(-1/2), alpha = 1-om
        const float om0 = __builtin_amdgcn_rsqf(1.0f + __expf(d0 + sh));
        const float om1 = __builtin_amdgcn_rsqf(1.0f + __expf(d1 + sh));
        const float om2 = __builtin_amdgcn_rsqf(1.0f + __expf(d2 + sh));
        const float om3 = __builtin_amdgcn_rsqf(1.0f + __expf(d3 + sh));
        const float al0 = 1.0f - om0, al1 = 1.0f - om1;
        const float al2 = 1.0f - om2, al3 = 1.0f - om3;

        // lane product, then wave-wide inclusive cumprod over lanes
        const float lp = (om0 * om1) * (om2 * om3);
        float p = lp;
        #pragma unroll
        for (int off = 1; off < 64; off <<= 1) {
            float q = __shfl_up(p, off, 64);
            if (lane >= off) p *= q;
        }
        float excl = __shfl_up(p, 1, 64);
        if (lane == 0) excl = 1.0f;

        // per-sample transmittance chain within the lane
        float t = carry * excl;
        const float w0 = al0 * t; t *= om0;
        const float w1 = al1 * t; t *= om1;
        const float w2 = al2 * t; t *= om2;
        const float w3 = al3 * t;

        // sigmoid(rgb) via native exp + rcp
        acc0 += w0 * __builtin_amdgcn_rcpf(1.0f + __expf(-r[0]))
              + w1 * __builtin_amdgcn_rcpf(1.0f + __expf(-r[3]))
              + w2 * __builtin_amdgcn_rcpf(1.0f + __expf(-r[6]))
              + w3 * __builtin_amdgcn_rcpf(1.0f + __expf(-r[9]));
        acc1 += w0 * __builtin_amdgcn_rcpf(1.0f + __expf(-r[1]))
              + w1 * __builtin_amdgcn_rcpf(1.0f + __expf(-r[4]))
              + w2 * __builtin_amdgcn_rcpf(1.0f + __expf(-r[7]))
              + w3 * __builtin_amdgcn_rcpf(1.0f + __expf(-r[10]));
        acc2 += w0 * __builtin_amdgcn_rcpf(1.0f + __expf(-r[2]))
              + w1 * __builtin_amdgcn_rcpf(1.0f + __expf(-r[5]))
              + w2 * __builtin_amdgcn_rcpf(1.0f + __expf(-r[8]))
              + w3 * __builtin_amdgcn_rcpf(1.0f + __expf(-r[11]));

        carry *= __shfl(p, 63, 64);
    }

    // wave reduction
    #pragma unroll
    for (int off = 32; off > 0; off >>= 1) {
        acc0 += __shfl_down(acc0, off, 64);
        acc1 += __shfl_down(acc1, off, 64);
        acc2 += __shfl_down(acc2, off, 64);
    }

    if (lane == 0) {
        out[3 * ray + 0] = acc0 + carry;
        out[3 * ray + 1] = acc1 + carry;
        out[3 * ray + 2] = acc2 + carry;
    }
}

extern "C" void kernel_launch(void* const* d_in, const int* in_sizes, int n_in,
                              void* d_out, int out_size, void* d_ws, size_t ws_size,
                              hipStream_t stream)
{
    const float* density = (const float*)d_in[0];
    const float* rgb_raw = (const float*)d_in[1];
    const float* shift   = (const float*)d_in[2];
    const int*   ray_id  = (const int*)d_in[3];
    float* out = (float*)d_out;

    const int M = in_sizes[0];
    const int N = out_size / 3;

    const int rays_per_block = 4;
    const int blocks = (N + rays_per_block - 1) / rays_per_block;
    voxel_march_kernel<<<blocks, 256, 0, stream>>>(density, rgb_raw, shift, ray_id,
                                                   out, M, N);
}

// Round 3
// 112.820 us; speedup vs baseline: 1.2186x; 1.1507x over previous
//
#include <hip/hip_runtime.h>
#include <math.h>

// Two-kernel plan:
//  k1 (seg_starts): starts[r] = first sample index of ray r, starts[N] = M.
//     One coalesced pass over ray_id; boundary threads range-fill (covers
//     empty rays). Replaces the 22-dependent-load binary search per wave.
//  k2 (voxel_march): one wave per ray, 4 samples/lane (256-sample chunks).
//     Branchless edge handling: loads are always address-safe (clamped to
//     M-4 at the tail); per-sample validity masks density to -1e30 ->
//     om=1, alpha=0, weight=0. No divergence.
//
// Math: om = exp(-0.5*softplus(x)) = rsqrt(1+exp(x)); alpha = 1-om.
// Transmittance: per-lane serial cumprod of 4 oms, 6-step shfl_up ladder over
// lane products, carry across chunks. out = sum w*sigmoid(rgb) + alphainv_last.

__device__ __forceinline__ float sigm(float x) {
    return __builtin_amdgcn_rcpf(1.0f + __expf(-x));
}

__global__ __launch_bounds__(256) void seg_starts_kernel(
    const int* __restrict__ ray_id, int* __restrict__ starts, int M, int N)
{
    const int i = blockIdx.x * 256 + threadIdx.x;
    if (i >= M) return;
    const int cur  = ray_id[i];
    const int prev = (i == 0) ? -1 : ray_id[i - 1];
    for (int r = prev + 1; r <= cur; ++r) starts[r] = i;  // no-op unless boundary
    if (i == M - 1) {
        for (int r = cur + 1; r <= N; ++r) starts[r] = M; // tail + sentinel
    }
}

template <bool USE_STARTS>
__global__ __launch_bounds__(256) void voxel_march_kernel(
    const float* __restrict__ density,
    const float* __restrict__ rgb_raw,
    const float* __restrict__ shift,
    const int*   __restrict__ ray_id,   // only used when !USE_STARTS
    const int*   __restrict__ starts,   // only used when USE_STARTS
    float* __restrict__ out,
    int M, int N)
{
    const int lane = threadIdx.x & 63;
    const int wave = threadIdx.x >> 6;
    const int ray  = blockIdx.x * 4 + wave;
    if (ray >= N) return;

    const float sh = shift[0];

    int begin, end;
    if (USE_STARTS) {
        begin = starts[ray];
        end   = starts[ray + 1];
    } else {
        // fallback: per-wave binary search (half-wave 0 -> lower_bound(ray),
        // half-wave 1 -> lower_bound(ray+1))
        int target = ray + (lane >= 32 ? 1 : 0);
        int lo = 0, len = M;
        while (len > 0) {
            int half = len >> 1;
            int mid  = lo + half;
            if (ray_id[mid] < target) { lo = mid + 1; len -= half + 1; }
            else                      { len = half; }
        }
        begin = __shfl(lo, 0, 64);
        end   = __shfl(lo, 32, 64);
    }

    float carry = 1.0f;
    float acc0 = 0.0f, acc1 = 0.0f, acc2 = 0.0f;

    for (int base = (begin & ~3); base < end; base += 256) {
        const int b4 = base + 4 * lane;          // this lane's 4 logical samples
        const int ba = min(b4, M - 4);           // address-safe (validity still uses b4)

        const float4 dd = *(const float4*)(density + ba);
        const float4* rp = (const float4*)(rgb_raw + 3 * ba);
        const float4 c0 = rp[0], c1 = rp[1], c2 = rp[2];

        // validity mask per original index; invalid -> density -1e30 -> om=1, alpha=0
        const bool v0 = (b4 + 0 >= begin) & (b4 + 0 < end);
        const bool v1 = (b4 + 1 >= begin) & (b4 + 1 < end);
        const bool v2 = (b4 + 2 >= begin) & (b4 + 2 < end);
        const bool v3 = (b4 + 3 >= begin) & (b4 + 3 < end);
        const float d0 = v0 ? dd.x : -1e30f;
        const float d1 = v1 ? dd.y : -1e30f;
        const float d2 = v2 ? dd.z : -1e30f;
        const float d3 = v3 ? dd.w : -1e30f;

        // om = (1+e^x)^(-1/2), alpha = 1-om
        const float om0 = __builtin_amdgcn_rsqf(1.0f + __expf(d0 + sh));
        const float om1 = __builtin_amdgcn_rsqf(1.0f + __expf(d1 + sh));
        const float om2 = __builtin_amdgcn_rsqf(1.0f + __expf(d2 + sh));
        const float om3 = __builtin_amdgcn_rsqf(1.0f + __expf(d3 + sh));
        const float al0 = 1.0f - om0, al1 = 1.0f - om1;
        const float al2 = 1.0f - om2, al3 = 1.0f - om3;

        // wave-wide inclusive cumprod over lane products
        const float lp = (om0 * om1) * (om2 * om3);
        float p = lp;
        #pragma unroll
        for (int off = 1; off < 64; off <<= 1) {
            float q = __shfl_up(p, off, 64);
            if (lane >= off) p *= q;
        }
        float excl = __shfl_up(p, 1, 64);
        if (lane == 0) excl = 1.0f;

        // per-sample transmittance within the lane
        float t = carry * excl;
        const float w0 = al0 * t; t *= om0;
        const float w1 = al1 * t; t *= om1;
        const float w2 = al2 * t; t *= om2;
        const float w3 = al3 * t;

        acc0 += w0 * sigm(c0.x) + w1 * sigm(c0.w) + w2 * sigm(c1.z) + w3 * sigm(c2.y);
        acc1 += w0 * sigm(c0.y) + w1 * sigm(c1.x) + w2 * sigm(c1.w) + w3 * sigm(c2.z);
        acc2 += w0 * sigm(c0.z) + w1 * sigm(c1.y) + w2 * sigm(c2.x) + w3 * sigm(c2.w);

        carry *= __shfl(p, 63, 64);
    }

    // wave reduction
    #pragma unroll
    for (int off = 32; off > 0; off >>= 1) {
        acc0 += __shfl_down(acc0, off, 64);
        acc1 += __shfl_down(acc1, off, 64);
        acc2 += __shfl_down(acc2, off, 64);
    }

    if (lane == 0) {
        out[3 * ray + 0] = acc0 + carry;   // + alphainv_last (white background)
        out[3 * ray + 1] = acc1 + carry;
        out[3 * ray + 2] = acc2 + carry;
    }
}

extern "C" void kernel_launch(void* const* d_in, const int* in_sizes, int n_in,
                              void* d_out, int out_size, void* d_ws, size_t ws_size,
                              hipStream_t stream)
{
    const float* density = (const float*)d_in[0];
    const float* rgb_raw = (const float*)d_in[1];
    const float* shift   = (const float*)d_in[2];
    const int*   ray_id  = (const int*)d_in[3];
    float* out = (float*)d_out;

    const int M = in_sizes[0];
    const int N = out_size / 3;

    const int rays_per_block = 4;
    const int blocks = (N + rays_per_block - 1) / rays_per_block;

    if (ws_size >= (size_t)(N + 1) * sizeof(int)) {
        int* starts = (int*)d_ws;
        seg_starts_kernel<<<(M + 255) / 256, 256, 0, stream>>>(ray_id, starts, M, N);
        voxel_march_kernel<true><<<blocks, 256, 0, stream>>>(
            density, rgb_raw, shift, ray_id, starts, out, M, N);
    } else {
        voxel_march_kernel<false><<<blocks, 256, 0, stream>>>(
            density, rgb_raw, shift, ray_id, (const int*)nullptr, out, M, N);
    }
}